// Round 16
// baseline (482.195 us; speedup 1.0000x reference)
//
#include <hip/hip_runtime.h>
#include <hip/hip_bf16.h>

#define NNODES 100000
#define NP (NNODES + 8)   // rows incl. zero rows (row NNODES = zero row)
#define NEDGES 1000000
#define HID 128
#define OUTF 16
#define NB 16        // dst-range buckets for CSR build
#define NBKT (NNODES / NB)  // 6250 nodes per bucket
#define BCAP 81920   // per-bucket stage capacity
#define BZT 1024     // bucketize block size
#define DB2 32       // degree bins per bucket
#define NBINS (NB * DB2)
#define NSL 4        // feature slices (32 features = 64 B rows)

typedef __attribute__((ext_vector_type(8))) short short8;
typedef __attribute__((ext_vector_type(4))) float floatx4;
typedef __attribute__((ext_vector_type(4))) unsigned int uintx4;
typedef unsigned int uint32;
typedef unsigned long long ull;
typedef unsigned short ushort16;

__device__ __forceinline__ float blo(uint32 u) { return __uint_as_float(u << 16); }
__device__ __forceinline__ float bhi(uint32 u) { return __uint_as_float(u & 0xffff0000u); }
__device__ __forceinline__ ushort16 f2b(float f) {
    __hip_bfloat16 h = __float2bfloat16(f);
    return *reinterpret_cast<ushort16*>(&h);
}
__device__ __forceinline__ uint32 pack2(float a, float b) {
    return (uint32)f2b(a) | ((uint32)f2b(b) << 16);
}

// ---------------- CSR build ----------------
// Pass A: bucket compaction only (no per-node atomics). Stage word: lo=src, hi=dst.

__global__ __launch_bounds__(BZT) void bucketize(const int* __restrict__ src,
                                                 const int* __restrict__ dst,
                                                 int* __restrict__ bcursor,
                                                 ull* __restrict__ stage, int E) {
    __shared__ int cnt[NB], lbase[NB], gbase[NB];
    __shared__ int2 buf[BZT];
    __shared__ unsigned char bb[BZT];
    int t = threadIdx.x;
    int e0 = blockIdx.x * BZT;
    int e = e0 + t;
    if (t < NB) cnt[t] = 0;
    __syncthreads();
    int s = 0, d = 0, b = 0, r = 0;
    bool valid = e < E;
    if (valid) {
        s = src[e];
        d = dst[e];
        b = d / NBKT;
        r = atomicAdd(&cnt[b], 1);
    }
    __syncthreads();
    if (t == 0) {
        int run = 0;
        for (int i = 0; i < NB; i++) { lbase[i] = run; run += cnt[i]; }
    }
    __syncthreads();
    if (valid) {
        int p = lbase[b] + r;
        buf[p] = make_int2(s, d);
        bb[p] = (unsigned char)b;
    }
    if (t < NB) gbase[t] = atomicAdd(&bcursor[t], cnt[t]);
    __syncthreads();
    int nvalid = min(BZT, E - e0);
    if (t < nvalid) {
        int b2 = bb[t];
        int2 sd = buf[t];
        int pos = gbase[b2] + (t - lbase[b2]);
        if (pos < BCAP) {
            ull val = (ull)(unsigned)sd.x | ((ull)(unsigned)sd.y << 32);
            __builtin_nontemporal_store(val, &stage[(size_t)b2 * BCAP + pos]);
        }
    }
}

// Pass B: per-bucket LDS degree histogram -> counts[] (no global atomics).

__global__ __launch_bounds__(1024) void bhist(const ull* __restrict__ stage,
                                              const int* __restrict__ bcursor,
                                              int* __restrict__ counts) {
    __shared__ int h[NBKT];  // 25 KB
    int b = blockIdx.x;
    int base = b * NBKT;
    for (int i = threadIdx.x; i < NBKT; i += 1024) h[i] = 0;
    __syncthreads();
    int cntb = min(bcursor[b], BCAP);
    const ull* st = stage + (size_t)b * BCAP;
    for (int i = threadIdx.x; i < cntb; i += 1024) {
        int d = (int)(unsigned)(st[i] >> 32);
        atomicAdd(&h[d - base], 1);
    }
    __syncthreads();
    for (int i = threadIdx.x; i < NBKT; i += 1024) counts[base + i] = h[i];
}

// Pass C: per-bucket LDS-cursor scatter to csr (bucket b -> XCD b%8, L2-local writes).

__global__ __launch_bounds__(1024) void bfill(const ull* __restrict__ stage,
                                              const int* __restrict__ bcursor,
                                              const int* __restrict__ perm,
                                              const int* __restrict__ offs,
                                              int* __restrict__ csr) {
    __shared__ int cur[NBKT];  // 25 KB
    int b = blockIdx.x;
    int base = b * NBKT;
    for (int i = threadIdx.x; i < NBKT; i += 1024) cur[i] = 0;
    __syncthreads();
    int cntb = min(bcursor[b], BCAP);
    const ull* st = stage + (size_t)b * BCAP;
    for (int i = threadIdx.x; i < cntb; i += 1024) {
        ull v = st[i];
        int s = (int)(v & 0xffffffffu);
        int d = (int)(unsigned)(v >> 32);
        int r = atomicAdd(&cur[d - base], 1);
        csr[offs[perm[d]] + r] = perm[s];
    }
}

// ---------------- per-bucket degree sort -> node relabeling ----------------

__global__ __launch_bounds__(256) void binhist(const int* __restrict__ counts,
                                               int* __restrict__ bins, int N) {
    __shared__ int h[NBINS];
    int t = threadIdx.x;
    for (int k = t; k < NBINS; k += 256) h[k] = 0;
    __syncthreads();
    int i = blockIdx.x * 256 + t;
    if (i < N) {
        int bi = i / NBKT;
        int db = min((counts[i] + 7) >> 3, DB2 - 1);
        atomicAdd(&h[bi * DB2 + db], 1);
    }
    __syncthreads();
    for (int k = t; k < NBINS; k += 256)
        if (h[k] > 0) atomicAdd(&bins[k], h[k]);
}

__global__ void binscan(int* __restrict__ bins) {
    if (threadIdx.x == 0) {
        int run = 0;
        for (int i = 0; i < NBINS; i++) {
            int c = bins[i];
            bins[i] = run;
            run += c;
        }
    }
}

__global__ __launch_bounds__(256) void dsort2(const int* __restrict__ counts,
                                              int* __restrict__ bins,
                                              int* __restrict__ perm,
                                              int* __restrict__ iperm,
                                              int* __restrict__ cnts_s, int N) {
    __shared__ int h[NBINS], lb[NBINS];
    int t = threadIdx.x;
    for (int k = t; k < NBINS; k += 256) h[k] = 0;
    __syncthreads();
    int i = blockIdx.x * 256 + t;
    int c = 0, idx = 0, r = 0;
    bool valid = i < N;
    if (valid) {
        c = counts[i];
        int bi = i / NBKT;
        idx = bi * DB2 + min((c + 7) >> 3, DB2 - 1);
        r = atomicAdd(&h[idx], 1);  // LDS local rank
    }
    __syncthreads();
    for (int k = t; k < NBINS; k += 256)
        lb[k] = (h[k] > 0) ? atomicAdd(&bins[k], h[k]) : 0;
    __syncthreads();
    if (valid) {
        int p = lb[idx] + r;
        perm[i] = p;
        iperm[p] = i;
        cnts_s[p] = c;
    }
}

// scan of sorted counts padded to 8 -> offs (32 B-aligned csr runs)
__global__ void scan1(const int* __restrict__ cnts_s, int* __restrict__ offs,
                      int* __restrict__ bsum, int N) {
    __shared__ int tmp[256];
    int t = threadIdx.x;
    int i = blockIdx.x * 256 + t;
    int v = (i < N) ? ((cnts_s[i] + 7) & ~7) : 0;
    tmp[t] = v;
    __syncthreads();
    for (int d = 1; d < 256; d <<= 1) {
        int add = (t >= d) ? tmp[t - d] : 0;
        __syncthreads();
        tmp[t] += add;
        __syncthreads();
    }
    if (i < N) offs[i] = tmp[t] - v;
    if (t == 255) bsum[blockIdx.x] = tmp[255];
}

__global__ void scan2(int* __restrict__ bsum, int nb) {
    __shared__ int tmp[512];
    int t = threadIdx.x;
    int v = (t < nb) ? bsum[t] : 0;
    tmp[t] = v;
    __syncthreads();
    for (int d = 1; d < 512; d <<= 1) {
        int add = (t >= d) ? tmp[t - d] : 0;
        __syncthreads();
        tmp[t] += add;
        __syncthreads();
    }
    if (t < nb) bsum[t] = tmp[t] - v;
}

// finalize offs, inv, and write csr pad entries (-> zero row)
__global__ void scan3(int* __restrict__ offs, const int* __restrict__ bsum,
                      const int* __restrict__ cnts_s, float* __restrict__ invs,
                      int* __restrict__ csr, int N) {
    int i = blockIdx.x * 256 + threadIdx.x;
    if (i < N) {
        int o = offs[i] + bsum[blockIdx.x];
        offs[i] = o;
        int c = cnts_s[i];
        invs[i] = 1.0f / (float)(c + 1);
        int c8 = (c + 7) & ~7;
        for (int k = c; k < c8; k++) csr[o + k] = NNODES;
    }
}

// ---------------- pack all weights + zero pad rows (one dispatch) ----------------

__global__ void pack_all(const float* __restrict__ W1, const float* __restrict__ W2,
                         const float* __restrict__ W3, const float* __restrict__ W4,
                         ushort16* __restrict__ Wp1, ushort16* __restrict__ Wp2,
                         ushort16* __restrict__ Wp3, ushort16* __restrict__ Wp4,
                         uint32* __restrict__ zb, uint32* __restrict__ hb,
                         uint32* __restrict__ z16b) {
    int blk = blockIdx.x;
    int lane = threadIdx.x;  // 64
    if (blk < 128) {
        int w = blk >> 5, b = blk & 31;
        const float* W = w == 0 ? W1 : w == 1 ? W2 : w == 2 ? W3 : W4;
        ushort16* Wp = w == 0 ? Wp1 : w == 1 ? Wp2 : w == 2 ? Wp3 : Wp4;
        int nt = b >> 2, ks = b & 3;
        int n = nt * 16 + (lane & 15);
        int kbase = ks * 32 + ((lane >> 4) << 3);
        ushort16 tmp[8];
#pragma unroll
        for (int i = 0; i < 8; i++) tmp[i] = f2b(W[(size_t)(kbase + i) * HID + n]);
        *(uint4*)&Wp[((size_t)b * 64 + lane) * 8] = *(uint4*)tmp;
    } else {
        for (int i = lane; i < 4 * 8 * 16; i += 64) {
            int s = i >> 7, rem = i & 127, r = rem >> 4, k = rem & 15;
            zb[((size_t)s * NP + NNODES + r) * 16 + k] = 0;
            hb[((size_t)s * NP + NNODES + r) * 16 + k] = 0;
        }
        for (int i = lane; i < 64; i += 64)
            z16b[(size_t)(NNODES + (i >> 3)) * 8 + (i & 7)] = 0;
    }
}

// ---------------- MFMA GEMM: Z(sliced [4][NP][32] bf16) = A @ W ----------------
// 256 rows per block (4 row-tiles), W staged to LDS once per block.

template <int AF32>
__global__ __launch_bounds__(256) void gemm_mfma(const void* __restrict__ Av,
                                                 const int* __restrict__ iperm,
                                                 const ushort16* __restrict__ Wp,
                                                 ushort16* __restrict__ Z, int M) {
    __shared__ __align__(16) ushort16 Wl[32 * 64 * 8];  // 32 KB
    int t = threadIdx.x;
    const uint4* wp4 = (const uint4*)Wp;
    uint4* wl4 = (uint4*)Wl;
#pragma unroll
    for (int p = 0; p < 8; p++) wl4[t + p * 256] = wp4[t + p * 256];
    __syncthreads();

    int wv = t >> 6, lane = t & 63;
    int kb = (lane >> 4) << 3;  // 0,8,16,24
    int c4 = (lane >> 4) << 2;  // 0,4,8,12

    for (int rt = 0; rt < 4; rt++) {
        int row = blockIdx.x * 256 + rt * 64 + wv * 16 + (lane & 15);
        int rowc = min(row, M - 1);

        short8 a[4];
        if (AF32) {
            const float* A = (const float*)Av;
            int orig = iperm[rowc];
#pragma unroll
            for (int ks = 0; ks < 4; ks++) {
                const float* p = A + (size_t)orig * HID + ks * 32 + kb;
                floatx4 lo = *(const floatx4*)p;
                floatx4 hi = *(const floatx4*)(p + 4);
                union { short8 s; ushort16 u[8]; } cv;
                cv.u[0] = f2b(lo.x); cv.u[1] = f2b(lo.y); cv.u[2] = f2b(lo.z); cv.u[3] = f2b(lo.w);
                cv.u[4] = f2b(hi.x); cv.u[5] = f2b(hi.y); cv.u[6] = f2b(hi.z); cv.u[7] = f2b(hi.w);
                a[ks] = cv.s;
            }
        } else {
            const ushort16* A = (const ushort16*)Av;
#pragma unroll
            for (int ks = 0; ks < 4; ks++)
                a[ks] = *(const short8*)(A + ((size_t)ks * NP + rowc) * 32 + kb);
        }

        floatx4 acc[8];
#pragma unroll
        for (int nt = 0; nt < 8; nt++) acc[nt] = (floatx4){0.f, 0.f, 0.f, 0.f};

#pragma unroll
        for (int nt = 0; nt < 8; nt++) {
#pragma unroll
            for (int ks = 0; ks < 4; ks++) {
                short8 w = *(const short8*)&Wl[(size_t)(((nt << 2) | ks) * 64 + lane) * 8];
                acc[nt] = __builtin_amdgcn_mfma_f32_16x16x32_bf16(w, a[ks], acc[nt], 0, 0, 0);
            }
        }

        if (row < M) {
#pragma unroll
            for (int nt = 0; nt < 8; nt++) {
                int col = nt * 16 + c4;
                int sl = col >> 5, off = col & 31;
                union { ushort16 u[4]; uint2 v; } pk;
                pk.u[0] = f2b(acc[nt][0]);
                pk.u[1] = f2b(acc[nt][1]);
                pk.u[2] = f2b(acc[nt][2]);
                pk.u[3] = f2b(acc[nt][3]);
                *(uint2*)&Z[((size_t)sl * NP + row) * 32 + off] = pk.v;
            }
        }
    }
}

// ---------------- sliced aggregate: 4 slices x 64 B rows, 4 lanes/node ----------------

#define ACCN(acc0, acc1, acc2, acc3, g)                \
    {                                                  \
        acc0.x += blo((g).x); acc0.y += bhi((g).x);    \
        acc1.x += blo((g).y); acc1.y += bhi((g).y);    \
        acc2.x += blo((g).z); acc2.y += bhi((g).z);    \
        acc3.x += blo((g).w); acc3.y += bhi((g).w);    \
    }

__global__ __launch_bounds__(256) void agg_sliced(const uint32* __restrict__ Z,
                                                  const int* __restrict__ offs,
                                                  const int* __restrict__ cnts_s,
                                                  const int* __restrict__ csr,
                                                  const float* __restrict__ invs,
                                                  const float* __restrict__ bias,
                                                  uint32* __restrict__ H, int N) {
    int s = blockIdx.x & 3;
    int chunk = blockIdx.x >> 2;
    int t = threadIdx.x;
    int l = t & 3;                // 16 B quarter of the 64 B row
    int p = chunk * 64 + (t >> 2);
    bool act = p < N;
    int pc = act ? p : N - 1;
    const uint4* Zs = (const uint4*)(Z + (size_t)s * NP * 16);
    uint4* Hs = (uint4*)(H + (size_t)s * NP * 16);

    int beg = offs[pc];
    int cnt8 = (cnts_s[pc] + 7) & ~7;
    float sc = invs[pc];

    uint4 sv = Zs[(size_t)pc * 4 + l];
    float2 acc0 = make_float2(blo(sv.x), bhi(sv.x));
    float2 acc1 = make_float2(blo(sv.y), bhi(sv.y));
    float2 acc2 = make_float2(blo(sv.z), bhi(sv.z));
    float2 acc3 = make_float2(blo(sv.w), bhi(sv.w));

    for (int j = 0; j < cnt8; j += 8) {
        int4 ia = *(const int4*)&csr[beg + j];
        int4 ib = *(const int4*)&csr[beg + j + 4];
        uint4 g[8];
        g[0] = Zs[(size_t)ia.x * 4 + l];
        g[1] = Zs[(size_t)ia.y * 4 + l];
        g[2] = Zs[(size_t)ia.z * 4 + l];
        g[3] = Zs[(size_t)ia.w * 4 + l];
        g[4] = Zs[(size_t)ib.x * 4 + l];
        g[5] = Zs[(size_t)ib.y * 4 + l];
        g[6] = Zs[(size_t)ib.z * 4 + l];
        g[7] = Zs[(size_t)ib.w * 4 + l];
#pragma unroll
        for (int q = 0; q < 8; q++) ACCN(acc0, acc1, acc2, acc3, g[q]);
    }

    const float* bp = bias + s * 32 + l * 8;
    floatx4 b01 = *(const floatx4*)bp;
    floatx4 b23 = *(const floatx4*)(bp + 4);
    uintx4 o;
    o.x = pack2(fmaxf(acc0.x * sc + b01.x, 0.f), fmaxf(acc0.y * sc + b01.y, 0.f));
    o.y = pack2(fmaxf(acc1.x * sc + b01.z, 0.f), fmaxf(acc1.y * sc + b01.w, 0.f));
    o.z = pack2(fmaxf(acc2.x * sc + b23.x, 0.f), fmaxf(acc2.y * sc + b23.y, 0.f));
    o.w = pack2(fmaxf(acc3.x * sc + b23.z, 0.f), fmaxf(acc3.y * sc + b23.w, 0.f));
    if (act) __builtin_nontemporal_store(o, (uintx4*)&Hs[(size_t)p * 4 + l]);
}

// ---------------- layer 5: Z16[NP][16] bf16 = H(sliced [4][NP][16u32]) @ W5 ----------------

__global__ __launch_bounds__(256) void gemm16(const uint32* __restrict__ A,
                                              const float* __restrict__ W5,
                                              uint32* __restrict__ Z16, int M) {
    __shared__ float Ws[HID * OUTF];  // 8 KB
    int t = threadIdx.x;
    for (int i = t; i < HID * OUTF; i += 256) Ws[i] = W5[i];
    __syncthreads();
    int gid = blockIdx.x * 256 + t;
    int r = gid >> 3, cp = gid & 7;
    if (r >= M) return;
    float a0 = 0.f, a1 = 0.f;
#pragma unroll
    for (int s4 = 0; s4 < 4; s4++) {
        const uint32* ar = A + ((size_t)s4 * NP + r) * 16;
#pragma unroll
        for (int k = 0; k < 16; k++) {
            uint32 u = ar[k];
            float f0 = blo(u), f1 = bhi(u);
            a0 += f0 * Ws[(s4 * 32 + 2 * k) * OUTF + 2 * cp] +
                  f1 * Ws[(s4 * 32 + 2 * k + 1) * OUTF + 2 * cp];
            a1 += f0 * Ws[(s4 * 32 + 2 * k) * OUTF + 2 * cp + 1] +
                  f1 * Ws[(s4 * 32 + 2 * k + 1) * OUTF + 2 * cp + 1];
        }
    }
    Z16[(size_t)r * 8 + cp] = pack2(a0, a1);
}

// ---------------- layer 5 aggregate + bias + log_softmax ----------------

__global__ __launch_bounds__(256) void agg16_lsm(const uint32* __restrict__ Z16,
                                                 const int* __restrict__ offs,
                                                 const int* __restrict__ cnts_s,
                                                 const int* __restrict__ csr,
                                                 const float* __restrict__ invs,
                                                 const int* __restrict__ iperm,
                                                 const float* __restrict__ b5,
                                                 float* __restrict__ out, int N) {
    int t = threadIdx.x;
    int l = t & 1;
    int p = blockIdx.x * 128 + (t >> 1);
    bool act = p < N;
    int pc = act ? p : N - 1;
    const uint4* Zs = (const uint4*)Z16;

    uint4 sv = Zs[(size_t)pc * 2 + l];
    float2 acc0 = make_float2(blo(sv.x), bhi(sv.x));
    float2 acc1 = make_float2(blo(sv.y), bhi(sv.y));
    float2 acc2 = make_float2(blo(sv.z), bhi(sv.z));
    float2 acc3 = make_float2(blo(sv.w), bhi(sv.w));

    int beg = offs[pc];
    int cnt8 = (cnts_s[pc] + 7) & ~7;
    for (int j = 0; j < cnt8; j += 8) {
        int4 ia = *(const int4*)&csr[beg + j];
        int4 ib = *(const int4*)&csr[beg + j + 4];
        uint4 g[8];
        g[0] = Zs[(size_t)ia.x * 2 + l];
        g[1] = Zs[(size_t)ia.y * 2 + l];
        g[2] = Zs[(size_t)ia.z * 2 + l];
        g[3] = Zs[(size_t)ia.w * 2 + l];
        g[4] = Zs[(size_t)ib.x * 2 + l];
        g[5] = Zs[(size_t)ib.y * 2 + l];
        g[6] = Zs[(size_t)ib.z * 2 + l];
        g[7] = Zs[(size_t)ib.w * 2 + l];
#pragma unroll
        for (int q = 0; q < 8; q++) ACCN(acc0, acc1, acc2, acc3, g[q]);
    }

    float sc = invs[pc];
    const float* bp = b5 + l * 8;
    floatx4 b01 = *(const floatx4*)bp;
    floatx4 b23 = *(const floatx4*)(bp + 4);
    float val[8];
    val[0] = acc0.x * sc + b01.x; val[1] = acc0.y * sc + b01.y;
    val[2] = acc1.x * sc + b01.z; val[3] = acc1.y * sc + b01.w;
    val[4] = acc2.x * sc + b23.x; val[5] = acc2.y * sc + b23.y;
    val[6] = acc3.x * sc + b23.z; val[7] = acc3.y * sc + b23.w;
    float mm = val[0];
#pragma unroll
    for (int k = 1; k < 8; k++) mm = fmaxf(mm, val[k]);
    mm = fmaxf(mm, __shfl_xor(mm, 1, 64));
    float ss = 0.f;
#pragma unroll
    for (int k = 0; k < 8; k++) ss += expf(val[k] - mm);
    ss += __shfl_xor(ss, 1, 64);
    float ls = mm + logf(ss);
    if (act) {
        int ov = iperm[p];
        float4 o0 = make_float4(val[0] - ls, val[1] - ls, val[2] - ls, val[3] - ls);
        float4 o1 = make_float4(val[4] - ls, val[5] - ls, val[6] - ls, val[7] - ls);
        float* op = out + (size_t)ov * OUTF + l * 8;
        *(float4*)op = o0;
        *(float4*)(op + 4) = o1;
    }
}

// ---------------- launch ----------------

extern "C" void kernel_launch(void* const* d_in, const int* in_sizes, int n_in,
                              void* d_out, int out_size, void* d_ws, size_t ws_size,
                              hipStream_t stream) {
    const float* x   = (const float*)d_in[0];
    const int*   src = (const int*)d_in[1];
    const int*   dst = (const int*)d_in[2];
    const float* W1 = (const float*)d_in[3];
    const float* b1 = (const float*)d_in[4];
    const float* W2 = (const float*)d_in[5];
    const float* b2 = (const float*)d_in[6];
    const float* W3 = (const float*)d_in[7];
    const float* b3 = (const float*)d_in[8];
    const float* W4 = (const float*)d_in[9];
    const float* b4 = (const float*)d_in[10];
    const float* W5 = (const float*)d_in[11];
    const float* b5 = (const float*)d_in[12];

    char* ws = (char*)d_ws;
    size_t off = 0;
    auto alloc = [&](size_t bytes) {
        void* p = ws + off;
        off = (off + bytes + 255) & ~(size_t)255;
        return p;
    };
    const size_t CSR_ELEMS = (size_t)NEDGES + 7 * (size_t)NNODES + 64;
    ushort16* zb   = (ushort16*)alloc((size_t)NSL * NP * 32 * 2);
    ushort16* hb   = (ushort16*)alloc((size_t)NSL * NP * 32 * 2);
    uint32*   z16b = (uint32*)alloc((size_t)NP * OUTF * 2);
    int*      counts = (int*)alloc((size_t)NNODES * 4);
    int*      cnts_s = (int*)alloc((size_t)NNODES * 4);
    int*      perm   = (int*)alloc((size_t)NNODES * 4);
    int*      iperm  = (int*)alloc((size_t)NNODES * 4);
    float*    invs   = (float*)alloc((size_t)NNODES * 4);
    int*      offs   = (int*)alloc((size_t)(NNODES + 1) * 4);
    int*      bsum   = (int*)alloc(512 * 4);
    int*      csr    = (int*)alloc(CSR_ELEMS * 4);
    ull*      stage  = (ull*)alloc((size_t)NB * BCAP * 8);
    int*      bcursor = (int*)alloc((NB + NBINS) * 4);
    int*      bins   = bcursor + NB;
    ushort16* Wp1 = (ushort16*)alloc((size_t)HID * HID * 2);
    ushort16* Wp2 = (ushort16*)alloc((size_t)HID * HID * 2);
    ushort16* Wp3 = (ushort16*)alloc((size_t)HID * HID * 2);
    ushort16* Wp4 = (ushort16*)alloc((size_t)HID * HID * 2);
    (void)ws_size; (void)in_sizes; (void)n_in; (void)out_size;

    const int N = NNODES, E = NEDGES;
    int nb = (N + 255) / 256;

    // CSR build + relabel (no per-edge global atomics anywhere)
    hipMemsetAsync(bcursor, 0, (NB + NBINS) * 4, stream);
    bucketize<<<(E + BZT - 1) / BZT, BZT, 0, stream>>>(src, dst, bcursor, stage, E);
    bhist<<<NB, 1024, 0, stream>>>(stage, bcursor, counts);
    binhist<<<nb, 256, 0, stream>>>(counts, bins, N);
    binscan<<<1, 64, 0, stream>>>(bins);
    dsort2<<<nb, 256, 0, stream>>>(counts, bins, perm, iperm, cnts_s, N);
    scan1<<<nb, 256, 0, stream>>>(cnts_s, offs, bsum, N);
    scan2<<<1, 512, 0, stream>>>(bsum, nb);
    scan3<<<nb, 256, 0, stream>>>(offs, bsum, cnts_s, invs, csr, N);
    bfill<<<NB, 1024, 0, stream>>>(stage, bcursor, perm, offs, csr);
    pack_all<<<129, 64, 0, stream>>>(W1, W2, W3, W4, Wp1, Wp2, Wp3, Wp4,
                                     (uint32*)zb, (uint32*)hb, z16b);

    int gemmGrid = (N + 255) / 256;
    int aggGrid  = NSL * ((N + 63) / 64);
    int agg16Grid = (N + 127) / 128;

    gemm_mfma<1><<<gemmGrid, 256, 0, stream>>>((const void*)x, iperm, Wp1, zb, N);
    agg_sliced<<<aggGrid, 256, 0, stream>>>((const uint32*)zb, offs, cnts_s, csr, invs, b1,
                                            (uint32*)hb, N);

    gemm_mfma<0><<<gemmGrid, 256, 0, stream>>>((const void*)hb, nullptr, Wp2, zb, N);
    agg_sliced<<<aggGrid, 256, 0, stream>>>((const uint32*)zb, offs, cnts_s, csr, invs, b2,
                                            (uint32*)hb, N);

    gemm_mfma<0><<<gemmGrid, 256, 0, stream>>>((const void*)hb, nullptr, Wp3, zb, N);
    agg_sliced<<<aggGrid, 256, 0, stream>>>((const uint32*)zb, offs, cnts_s, csr, invs, b3,
                                            (uint32*)hb, N);

    gemm_mfma<0><<<gemmGrid, 256, 0, stream>>>((const void*)hb, nullptr, Wp4, zb, N);
    agg_sliced<<<aggGrid, 256, 0, stream>>>((const uint32*)zb, offs, cnts_s, csr, invs, b4,
                                            (uint32*)hb, N);

    gemm16<<<(N * 8 + 255) / 256, 256, 0, stream>>>((const uint32*)hb, W5, z16b, N);
    agg16_lsm<<<agg16Grid, 256, 0, stream>>>(z16b, offs, cnts_s, csr, invs, iperm, b5,
                                             (float*)d_out, N);
}

// Round 17
// 371.873 us; speedup vs baseline: 1.2967x; 1.2967x over previous
//
#include <hip/hip_runtime.h>
#include <hip/hip_bf16.h>

#define NNODES 100000
#define NP (NNODES + 8)   // rows incl. zero rows (row NNODES = zero row)
#define NEDGES 1000000
#define HID 128
#define OUTF 16
#define NB 16        // dst-range buckets for CSR build
#define NBKT (NNODES / NB)
#define BCAP 81920   // per-bucket stage capacity
#define KB 64        // blocks per bucket in count_rank/fill2
#define BZT 1024     // bucketize block size
#define DB2 32       // degree bins per bucket
#define NBINS (NB * DB2)
#define NSL 4        // feature slices (32 features = 64 B rows)

typedef __attribute__((ext_vector_type(8))) short short8;
typedef __attribute__((ext_vector_type(4))) float floatx4;
typedef __attribute__((ext_vector_type(4))) unsigned int uintx4;
typedef unsigned int uint32;
typedef unsigned long long ull;
typedef unsigned short ushort16;

__device__ __forceinline__ float blo(uint32 u) { return __uint_as_float(u << 16); }
__device__ __forceinline__ float bhi(uint32 u) { return __uint_as_float(u & 0xffff0000u); }
__device__ __forceinline__ ushort16 f2b(float f) {
    __hip_bfloat16 h = __float2bfloat16(f);
    return *reinterpret_cast<ushort16*>(&h);
}
__device__ __forceinline__ uint32 pack2(float a, float b) {
    return (uint32)f2b(a) | ((uint32)f2b(b) << 16);
}

// ---------------- CSR build ----------------
// Pass A: bucket compaction only. Stage word: lo=src, hi=dst.

__global__ __launch_bounds__(BZT) void bucketize(const int* __restrict__ src,
                                                 const int* __restrict__ dst,
                                                 int* __restrict__ bcursor,
                                                 ull* __restrict__ stage, int E) {
    __shared__ int cnt[NB], lbase[NB], gbase[NB];
    __shared__ int2 buf[BZT];
    __shared__ unsigned char bb[BZT];
    int t = threadIdx.x;
    int e0 = blockIdx.x * BZT;
    int e = e0 + t;
    if (t < NB) cnt[t] = 0;
    __syncthreads();
    int s = 0, d = 0, b = 0, r = 0;
    bool valid = e < E;
    if (valid) {
        s = src[e];
        d = dst[e];
        b = d / NBKT;
        r = atomicAdd(&cnt[b], 1);
    }
    __syncthreads();
    if (t == 0) {
        int run = 0;
        for (int i = 0; i < NB; i++) { lbase[i] = run; run += cnt[i]; }
    }
    __syncthreads();
    if (valid) {
        int p = lbase[b] + r;
        buf[p] = make_int2(s, d);
        bb[p] = (unsigned char)b;
    }
    if (t < NB) gbase[t] = atomicAdd(&bcursor[t], cnt[t]);
    __syncthreads();
    int nvalid = min(BZT, E - e0);
    if (t < nvalid) {
        int b2 = bb[t];
        int2 sd = buf[t];
        int pos = gbase[b2] + (t - lbase[b2]);
        if (pos < BCAP) {
            ull val = (ull)(unsigned)sd.x | ((ull)(unsigned)sd.y << 32);
            __builtin_nontemporal_store(val, &stage[(size_t)b2 * BCAP + pos]);
        }
    }
}

// Pass B: per-node degree count + rank, XCD-local atomics (bucket b -> XCD b%8).

__global__ __launch_bounds__(256) void count_rank(const ull* __restrict__ stage,
                                                  const int* __restrict__ bcursor,
                                                  int* __restrict__ counts,
                                                  int* __restrict__ rnk) {
    int blk = blockIdx.x;
    int b = (blk & 7) + 8 * ((blk >> 3) & 1);  // home XCD = b%8
    int slot = blk >> 4;
    int cntb = min(bcursor[b], BCAP);
    int per = (cntb + KB - 1) / KB;
    int s0 = slot * per;
    int s1 = min(s0 + per, cntb);
    const ull* st = stage + (size_t)b * BCAP;
    int* rk = rnk + (size_t)b * BCAP;
    for (int i = s0 + threadIdx.x; i < s1; i += 256) {
        ull v = st[i];
        int d = (int)(unsigned)(v >> 32);
        rk[i] = atomicAdd(&counts[d], 1);
    }
}

// Pass C: atomic-free scatter within bucket's csr window.

__global__ __launch_bounds__(256) void fill2(const ull* __restrict__ stage,
                                             const int* __restrict__ rnk,
                                             const int* __restrict__ bcursor,
                                             const int* __restrict__ perm,
                                             const int* __restrict__ offs,
                                             int* __restrict__ csr) {
    int blk = blockIdx.x;
    int b = (blk & 7) + 8 * ((blk >> 3) & 1);
    int slot = blk >> 4;
    int cntb = min(bcursor[b], BCAP);
    int per = (cntb + KB - 1) / KB;
    int s0 = slot * per;
    int s1 = min(s0 + per, cntb);
    const ull* st = stage + (size_t)b * BCAP;
    const int* rk = rnk + (size_t)b * BCAP;
    for (int i = s0 + threadIdx.x; i < s1; i += 256) {
        ull v = st[i];
        int s = (int)(v & 0xffffffffu);
        int d = (int)(unsigned)(v >> 32);
        int pd = perm[d];
        csr[offs[pd] + rk[i]] = perm[s];
    }
}

// ---------------- per-bucket degree sort -> node relabeling ----------------

__global__ __launch_bounds__(256) void binhist(const int* __restrict__ counts,
                                               int* __restrict__ bins, int N) {
    __shared__ int h[NBINS];
    int t = threadIdx.x;
    for (int k = t; k < NBINS; k += 256) h[k] = 0;
    __syncthreads();
    int i = blockIdx.x * 256 + t;
    if (i < N) {
        int bi = i / NBKT;
        int db = min((counts[i] + 7) >> 3, DB2 - 1);
        atomicAdd(&h[bi * DB2 + db], 1);
    }
    __syncthreads();
    for (int k = t; k < NBINS; k += 256)
        if (h[k] > 0) atomicAdd(&bins[k], h[k]);
}

__global__ void binscan(int* __restrict__ bins) {
    if (threadIdx.x == 0) {
        int run = 0;
        for (int i = 0; i < NBINS; i++) {
            int c = bins[i];
            bins[i] = run;
            run += c;
        }
    }
}

__global__ __launch_bounds__(256) void dsort2(const int* __restrict__ counts,
                                              int* __restrict__ bins,
                                              int* __restrict__ perm,
                                              int* __restrict__ iperm,
                                              int* __restrict__ cnts_s, int N) {
    __shared__ int h[NBINS], lb[NBINS];
    int t = threadIdx.x;
    for (int k = t; k < NBINS; k += 256) h[k] = 0;
    __syncthreads();
    int i = blockIdx.x * 256 + t;
    int c = 0, idx = 0, r = 0;
    bool valid = i < N;
    if (valid) {
        c = counts[i];
        int bi = i / NBKT;
        idx = bi * DB2 + min((c + 7) >> 3, DB2 - 1);
        r = atomicAdd(&h[idx], 1);  // LDS local rank
    }
    __syncthreads();
    for (int k = t; k < NBINS; k += 256)
        lb[k] = (h[k] > 0) ? atomicAdd(&bins[k], h[k]) : 0;
    __syncthreads();
    if (valid) {
        int p = lb[idx] + r;
        perm[i] = p;
        iperm[p] = i;
        cnts_s[p] = c;
    }
}

// scan of sorted counts padded to 8 -> offs (32 B-aligned csr runs)
__global__ void scan1(const int* __restrict__ cnts_s, int* __restrict__ offs,
                      int* __restrict__ bsum, int N) {
    __shared__ int tmp[256];
    int t = threadIdx.x;
    int i = blockIdx.x * 256 + t;
    int v = (i < N) ? ((cnts_s[i] + 7) & ~7) : 0;
    tmp[t] = v;
    __syncthreads();
    for (int d = 1; d < 256; d <<= 1) {
        int add = (t >= d) ? tmp[t - d] : 0;
        __syncthreads();
        tmp[t] += add;
        __syncthreads();
    }
    if (i < N) offs[i] = tmp[t] - v;
    if (t == 255) bsum[blockIdx.x] = tmp[255];
}

__global__ void scan2(int* __restrict__ bsum, int nb) {
    __shared__ int tmp[512];
    int t = threadIdx.x;
    int v = (t < nb) ? bsum[t] : 0;
    tmp[t] = v;
    __syncthreads();
    for (int d = 1; d < 512; d <<= 1) {
        int add = (t >= d) ? tmp[t - d] : 0;
        __syncthreads();
        tmp[t] += add;
        __syncthreads();
    }
    if (t < nb) bsum[t] = tmp[t] - v;
}

// finalize offs, inv, and write csr pad entries (-> zero row)
__global__ void scan3(int* __restrict__ offs, const int* __restrict__ bsum,
                      const int* __restrict__ cnts_s, float* __restrict__ invs,
                      int* __restrict__ csr, int N) {
    int i = blockIdx.x * 256 + threadIdx.x;
    if (i < N) {
        int o = offs[i] + bsum[blockIdx.x];
        offs[i] = o;
        int c = cnts_s[i];
        invs[i] = 1.0f / (float)(c + 1);
        int c8 = (c + 7) & ~7;
        for (int k = c; k < c8; k++) csr[o + k] = NNODES;
    }
}

// ---------------- pack all weights + zero pad rows (one dispatch) ----------------

__global__ void pack_all(const float* __restrict__ W1, const float* __restrict__ W2,
                         const float* __restrict__ W3, const float* __restrict__ W4,
                         ushort16* __restrict__ Wp1, ushort16* __restrict__ Wp2,
                         ushort16* __restrict__ Wp3, ushort16* __restrict__ Wp4,
                         uint32* __restrict__ zb, uint32* __restrict__ hb,
                         uint32* __restrict__ z16b) {
    int blk = blockIdx.x;
    int lane = threadIdx.x;  // 64
    if (blk < 128) {
        int w = blk >> 5, b = blk & 31;
        const float* W = w == 0 ? W1 : w == 1 ? W2 : w == 2 ? W3 : W4;
        ushort16* Wp = w == 0 ? Wp1 : w == 1 ? Wp2 : w == 2 ? Wp3 : Wp4;
        int nt = b >> 2, ks = b & 3;
        int n = nt * 16 + (lane & 15);
        int kbase = ks * 32 + ((lane >> 4) << 3);
        ushort16 tmp[8];
#pragma unroll
        for (int i = 0; i < 8; i++) tmp[i] = f2b(W[(size_t)(kbase + i) * HID + n]);
        *(uint4*)&Wp[((size_t)b * 64 + lane) * 8] = *(uint4*)tmp;
    } else {
        for (int i = lane; i < 4 * 8 * 16; i += 64) {
            int s = i >> 7, rem = i & 127, r = rem >> 4, k = rem & 15;
            zb[((size_t)s * NP + NNODES + r) * 16 + k] = 0;
            hb[((size_t)s * NP + NNODES + r) * 16 + k] = 0;
        }
        for (int i = lane; i < 64; i += 64)
            z16b[(size_t)(NNODES + (i >> 3)) * 8 + (i & 7)] = 0;
    }
}

// ---------------- MFMA GEMM: Z(sliced [4][NP][32] bf16) = A @ W ----------------
// 256 rows per block (4 row-tiles), W staged to LDS once per block.

template <int AF32>
__global__ __launch_bounds__(256) void gemm_mfma(const void* __restrict__ Av,
                                                 const int* __restrict__ iperm,
                                                 const ushort16* __restrict__ Wp,
                                                 ushort16* __restrict__ Z, int M) {
    __shared__ __align__(16) ushort16 Wl[32 * 64 * 8];  // 32 KB
    int t = threadIdx.x;
    const uint4* wp4 = (const uint4*)Wp;
    uint4* wl4 = (uint4*)Wl;
#pragma unroll
    for (int p = 0; p < 8; p++) wl4[t + p * 256] = wp4[t + p * 256];
    __syncthreads();

    int wv = t >> 6, lane = t & 63;
    int kb = (lane >> 4) << 3;  // 0,8,16,24
    int c4 = (lane >> 4) << 2;  // 0,4,8,12

    for (int rt = 0; rt < 4; rt++) {
        int row = blockIdx.x * 256 + rt * 64 + wv * 16 + (lane & 15);
        int rowc = min(row, M - 1);

        short8 a[4];
        if (AF32) {
            const float* A = (const float*)Av;
            int orig = iperm[rowc];
#pragma unroll
            for (int ks = 0; ks < 4; ks++) {
                const float* p = A + (size_t)orig * HID + ks * 32 + kb;
                floatx4 lo = *(const floatx4*)p;
                floatx4 hi = *(const floatx4*)(p + 4);
                union { short8 s; ushort16 u[8]; } cv;
                cv.u[0] = f2b(lo.x); cv.u[1] = f2b(lo.y); cv.u[2] = f2b(lo.z); cv.u[3] = f2b(lo.w);
                cv.u[4] = f2b(hi.x); cv.u[5] = f2b(hi.y); cv.u[6] = f2b(hi.z); cv.u[7] = f2b(hi.w);
                a[ks] = cv.s;
            }
        } else {
            const ushort16* A = (const ushort16*)Av;
#pragma unroll
            for (int ks = 0; ks < 4; ks++)
                a[ks] = *(const short8*)(A + ((size_t)ks * NP + rowc) * 32 + kb);
        }

        floatx4 acc[8];
#pragma unroll
        for (int nt = 0; nt < 8; nt++) acc[nt] = (floatx4){0.f, 0.f, 0.f, 0.f};

#pragma unroll
        for (int nt = 0; nt < 8; nt++) {
#pragma unroll
            for (int ks = 0; ks < 4; ks++) {
                short8 w = *(const short8*)&Wl[(size_t)(((nt << 2) | ks) * 64 + lane) * 8];
                acc[nt] = __builtin_amdgcn_mfma_f32_16x16x32_bf16(w, a[ks], acc[nt], 0, 0, 0);
            }
        }

        if (row < M) {
#pragma unroll
            for (int nt = 0; nt < 8; nt++) {
                int col = nt * 16 + c4;
                int sl = col >> 5, off = col & 31;
                union { ushort16 u[4]; uint2 v; } pk;
                pk.u[0] = f2b(acc[nt][0]);
                pk.u[1] = f2b(acc[nt][1]);
                pk.u[2] = f2b(acc[nt][2]);
                pk.u[3] = f2b(acc[nt][3]);
                *(uint2*)&Z[((size_t)sl * NP + row) * 32 + off] = pk.v;
            }
        }
    }
}

// ---------------- sliced aggregate: 4 slices x 64 B rows, 4 lanes/node ----------------

#define ACCN(acc0, acc1, acc2, acc3, g)                \
    {                                                  \
        acc0.x += blo((g).x); acc0.y += bhi((g).x);    \
        acc1.x += blo((g).y); acc1.y += bhi((g).y);    \
        acc2.x += blo((g).z); acc2.y += bhi((g).z);    \
        acc3.x += blo((g).w); acc3.y += bhi((g).w);    \
    }

__global__ __launch_bounds__(256) void agg_sliced(const uint32* __restrict__ Z,
                                                  const int* __restrict__ offs,
                                                  const int* __restrict__ cnts_s,
                                                  const int* __restrict__ csr,
                                                  const float* __restrict__ invs,
                                                  const float* __restrict__ bias,
                                                  uint32* __restrict__ H, int N) {
    int s = blockIdx.x & 3;
    int chunk = blockIdx.x >> 2;
    int t = threadIdx.x;
    int l = t & 3;                // 16 B quarter of the 64 B row
    int p = chunk * 64 + (t >> 2);
    bool act = p < N;
    int pc = act ? p : N - 1;
    const uint4* Zs = (const uint4*)(Z + (size_t)s * NP * 16);
    uint4* Hs = (uint4*)(H + (size_t)s * NP * 16);

    int beg = offs[pc];
    int cnt8 = (cnts_s[pc] + 7) & ~7;
    float sc = invs[pc];

    uint4 sv = Zs[(size_t)pc * 4 + l];
    float2 acc0 = make_float2(blo(sv.x), bhi(sv.x));
    float2 acc1 = make_float2(blo(sv.y), bhi(sv.y));
    float2 acc2 = make_float2(blo(sv.z), bhi(sv.z));
    float2 acc3 = make_float2(blo(sv.w), bhi(sv.w));

    for (int j = 0; j < cnt8; j += 8) {
        int4 ia = *(const int4*)&csr[beg + j];
        int4 ib = *(const int4*)&csr[beg + j + 4];
        uint4 g[8];
        g[0] = Zs[(size_t)ia.x * 4 + l];
        g[1] = Zs[(size_t)ia.y * 4 + l];
        g[2] = Zs[(size_t)ia.z * 4 + l];
        g[3] = Zs[(size_t)ia.w * 4 + l];
        g[4] = Zs[(size_t)ib.x * 4 + l];
        g[5] = Zs[(size_t)ib.y * 4 + l];
        g[6] = Zs[(size_t)ib.z * 4 + l];
        g[7] = Zs[(size_t)ib.w * 4 + l];
#pragma unroll
        for (int q = 0; q < 8; q++) ACCN(acc0, acc1, acc2, acc3, g[q]);
    }

    const float* bp = bias + s * 32 + l * 8;
    floatx4 b01 = *(const floatx4*)bp;
    floatx4 b23 = *(const floatx4*)(bp + 4);
    uintx4 o;
    o.x = pack2(fmaxf(acc0.x * sc + b01.x, 0.f), fmaxf(acc0.y * sc + b01.y, 0.f));
    o.y = pack2(fmaxf(acc1.x * sc + b01.z, 0.f), fmaxf(acc1.y * sc + b01.w, 0.f));
    o.z = pack2(fmaxf(acc2.x * sc + b23.x, 0.f), fmaxf(acc2.y * sc + b23.y, 0.f));
    o.w = pack2(fmaxf(acc3.x * sc + b23.z, 0.f), fmaxf(acc3.y * sc + b23.w, 0.f));
    if (act) __builtin_nontemporal_store(o, (uintx4*)&Hs[(size_t)p * 4 + l]);
}

// ---------------- layer 5: Z16[NP][16] bf16 = H(sliced [4][NP][16u32]) @ W5 ----------------

__global__ __launch_bounds__(256) void gemm16(const uint32* __restrict__ A,
                                              const float* __restrict__ W5,
                                              uint32* __restrict__ Z16, int M) {
    __shared__ float Ws[HID * OUTF];  // 8 KB
    int t = threadIdx.x;
    for (int i = t; i < HID * OUTF; i += 256) Ws[i] = W5[i];
    __syncthreads();
    int gid = blockIdx.x * 256 + t;
    int r = gid >> 3, cp = gid & 7;
    if (r >= M) return;
    float a0 = 0.f, a1 = 0.f;
#pragma unroll
    for (int s4 = 0; s4 < 4; s4++) {
        const uint32* ar = A + ((size_t)s4 * NP + r) * 16;
#pragma unroll
        for (int k = 0; k < 16; k++) {
            uint32 u = ar[k];
            float f0 = blo(u), f1 = bhi(u);
            a0 += f0 * Ws[(s4 * 32 + 2 * k) * OUTF + 2 * cp] +
                  f1 * Ws[(s4 * 32 + 2 * k + 1) * OUTF + 2 * cp];
            a1 += f0 * Ws[(s4 * 32 + 2 * k) * OUTF + 2 * cp + 1] +
                  f1 * Ws[(s4 * 32 + 2 * k + 1) * OUTF + 2 * cp + 1];
        }
    }
    Z16[(size_t)r * 8 + cp] = pack2(a0, a1);
}

// ---------------- layer 5 aggregate + bias + log_softmax ----------------

__global__ __launch_bounds__(256) void agg16_lsm(const uint32* __restrict__ Z16,
                                                 const int* __restrict__ offs,
                                                 const int* __restrict__ cnts_s,
                                                 const int* __restrict__ csr,
                                                 const float* __restrict__ invs,
                                                 const int* __restrict__ iperm,
                                                 const float* __restrict__ b5,
                                                 float* __restrict__ out, int N) {
    int t = threadIdx.x;
    int l = t & 1;
    int p = blockIdx.x * 128 + (t >> 1);
    bool act = p < N;
    int pc = act ? p : N - 1;
    const uint4* Zs = (const uint4*)Z16;

    uint4 sv = Zs[(size_t)pc * 2 + l];
    float2 acc0 = make_float2(blo(sv.x), bhi(sv.x));
    float2 acc1 = make_float2(blo(sv.y), bhi(sv.y));
    float2 acc2 = make_float2(blo(sv.z), bhi(sv.z));
    float2 acc3 = make_float2(blo(sv.w), bhi(sv.w));

    int beg = offs[pc];
    int cnt8 = (cnts_s[pc] + 7) & ~7;
    for (int j = 0; j < cnt8; j += 8) {
        int4 ia = *(const int4*)&csr[beg + j];
        int4 ib = *(const int4*)&csr[beg + j + 4];
        uint4 g[8];
        g[0] = Zs[(size_t)ia.x * 2 + l];
        g[1] = Zs[(size_t)ia.y * 2 + l];
        g[2] = Zs[(size_t)ia.z * 2 + l];
        g[3] = Zs[(size_t)ia.w * 2 + l];
        g[4] = Zs[(size_t)ib.x * 2 + l];
        g[5] = Zs[(size_t)ib.y * 2 + l];
        g[6] = Zs[(size_t)ib.z * 2 + l];
        g[7] = Zs[(size_t)ib.w * 2 + l];
#pragma unroll
        for (int q = 0; q < 8; q++) ACCN(acc0, acc1, acc2, acc3, g[q]);
    }

    float sc = invs[pc];
    const float* bp = b5 + l * 8;
    floatx4 b01 = *(const floatx4*)bp;
    floatx4 b23 = *(const floatx4*)(bp + 4);
    float val[8];
    val[0] = acc0.x * sc + b01.x; val[1] = acc0.y * sc + b01.y;
    val[2] = acc1.x * sc + b01.z; val[3] = acc1.y * sc + b01.w;
    val[4] = acc2.x * sc + b23.x; val[5] = acc2.y * sc + b23.y;
    val[6] = acc3.x * sc + b23.z; val[7] = acc3.y * sc + b23.w;
    float mm = val[0];
#pragma unroll
    for (int k = 1; k < 8; k++) mm = fmaxf(mm, val[k]);
    mm = fmaxf(mm, __shfl_xor(mm, 1, 64));
    float ss = 0.f;
#pragma unroll
    for (int k = 0; k < 8; k++) ss += expf(val[k] - mm);
    ss += __shfl_xor(ss, 1, 64);
    float ls = mm + logf(ss);
    if (act) {
        int ov = iperm[p];
        float4 o0 = make_float4(val[0] - ls, val[1] - ls, val[2] - ls, val[3] - ls);
        float4 o1 = make_float4(val[4] - ls, val[5] - ls, val[6] - ls, val[7] - ls);
        float* op = out + (size_t)ov * OUTF + l * 8;
        *(float4*)op = o0;
        *(float4*)(op + 4) = o1;
    }
}

// ---------------- launch ----------------

extern "C" void kernel_launch(void* const* d_in, const int* in_sizes, int n_in,
                              void* d_out, int out_size, void* d_ws, size_t ws_size,
                              hipStream_t stream) {
    const float* x   = (const float*)d_in[0];
    const int*   src = (const int*)d_in[1];
    const int*   dst = (const int*)d_in[2];
    const float* W1 = (const float*)d_in[3];
    const float* b1 = (const float*)d_in[4];
    const float* W2 = (const float*)d_in[5];
    const float* b2 = (const float*)d_in[6];
    const float* W3 = (const float*)d_in[7];
    const float* b3 = (const float*)d_in[8];
    const float* W4 = (const float*)d_in[9];
    const float* b4 = (const float*)d_in[10];
    const float* W5 = (const float*)d_in[11];
    const float* b5 = (const float*)d_in[12];

    char* ws = (char*)d_ws;
    size_t off = 0;
    auto alloc = [&](size_t bytes) {
        void* p = ws + off;
        off = (off + bytes + 255) & ~(size_t)255;
        return p;
    };
    const size_t CSR_ELEMS = (size_t)NEDGES + 7 * (size_t)NNODES + 64;
    ushort16* zb   = (ushort16*)alloc((size_t)NSL * NP * 32 * 2);
    ushort16* hb   = (ushort16*)alloc((size_t)NSL * NP * 32 * 2);
    uint32*   z16b = (uint32*)alloc((size_t)NP * OUTF * 2);
    int*      counts = (int*)alloc((size_t)NNODES * 4);
    int*      cnts_s = (int*)alloc((size_t)NNODES * 4);
    int*      perm   = (int*)alloc((size_t)NNODES * 4);
    int*      iperm  = (int*)alloc((size_t)NNODES * 4);
    float*    invs   = (float*)alloc((size_t)NNODES * 4);
    int*      offs   = (int*)alloc((size_t)(NNODES + 1) * 4);
    int*      bsum   = (int*)alloc(512 * 4);
    int*      csr    = (int*)alloc(CSR_ELEMS * 4);
    ull*      stage  = (ull*)alloc((size_t)NB * BCAP * 8);
    int*      rnk    = (int*)alloc((size_t)NB * BCAP * 4);
    int*      bcursor = (int*)alloc((NB + NBINS) * 4);
    int*      bins   = bcursor + NB;
    ushort16* Wp1 = (ushort16*)alloc((size_t)HID * HID * 2);
    ushort16* Wp2 = (ushort16*)alloc((size_t)HID * HID * 2);
    ushort16* Wp3 = (ushort16*)alloc((size_t)HID * HID * 2);
    ushort16* Wp4 = (ushort16*)alloc((size_t)HID * HID * 2);
    (void)ws_size; (void)in_sizes; (void)n_in; (void)out_size;

    const int N = NNODES, E = NEDGES;
    int nb = (N + 255) / 256;

    // CSR build + relabel
    hipMemsetAsync(counts, 0, (size_t)N * 4, stream);
    hipMemsetAsync(bcursor, 0, (NB + NBINS) * 4, stream);
    bucketize<<<(E + BZT - 1) / BZT, BZT, 0, stream>>>(src, dst, bcursor, stage, E);
    count_rank<<<NB * KB, 256, 0, stream>>>(stage, bcursor, counts, rnk);
    binhist<<<nb, 256, 0, stream>>>(counts, bins, N);
    binscan<<<1, 64, 0, stream>>>(bins);
    dsort2<<<nb, 256, 0, stream>>>(counts, bins, perm, iperm, cnts_s, N);
    scan1<<<nb, 256, 0, stream>>>(cnts_s, offs, bsum, N);
    scan2<<<1, 512, 0, stream>>>(bsum, nb);
    scan3<<<nb, 256, 0, stream>>>(offs, bsum, cnts_s, invs, csr, N);
    fill2<<<NB * KB, 256, 0, stream>>>(stage, rnk, bcursor, perm, offs, csr);
    pack_all<<<129, 64, 0, stream>>>(W1, W2, W3, W4, Wp1, Wp2, Wp3, Wp4,
                                     (uint32*)zb, (uint32*)hb, z16b);

    int gemmGrid = (N + 255) / 256;
    int aggGrid  = NSL * ((N + 63) / 64);
    int agg16Grid = (N + 127) / 128;

    gemm_mfma<1><<<gemmGrid, 256, 0, stream>>>((const void*)x, iperm, Wp1, zb, N);
    agg_sliced<<<aggGrid, 256, 0, stream>>>((const uint32*)zb, offs, cnts_s, csr, invs, b1,
                                            (uint32*)hb, N);

    gemm_mfma<0><<<gemmGrid, 256, 0, stream>>>((const void*)hb, nullptr, Wp2, zb, N);
    agg_sliced<<<aggGrid, 256, 0, stream>>>((const uint32*)zb, offs, cnts_s, csr, invs, b2,
                                            (uint32*)hb, N);

    gemm_mfma<0><<<gemmGrid, 256, 0, stream>>>((const void*)hb, nullptr, Wp3, zb, N);
    agg_sliced<<<aggGrid, 256, 0, stream>>>((const uint32*)zb, offs, cnts_s, csr, invs, b3,
                                            (uint32*)hb, N);

    gemm_mfma<0><<<gemmGrid, 256, 0, stream>>>((const void*)hb, nullptr, Wp4, zb, N);
    agg_sliced<<<aggGrid, 256, 0, stream>>>((const uint32*)zb, offs, cnts_s, csr, invs, b4,
                                            (uint32*)hb, N);

    gemm16<<<(N * 8 + 255) / 256, 256, 0, stream>>>((const uint32*)hb, W5, z16b, N);
    agg16_lsm<<<agg16Grid, 256, 0, stream>>>(z16b, offs, cnts_s, csr, invs, iperm, b5,
                                             (float*)d_out, N);
}

// Round 18
// 342.588 us; speedup vs baseline: 1.4075x; 1.0855x over previous
//
#include <hip/hip_runtime.h>
#include <hip/hip_bf16.h>

#define NNODES 100000
#define NP (NNODES + 8)   // rows incl. zero rows (row NNODES = zero row)
#define NEDGES 1000000
#define HID 128
#define OUTF 16
#define NB 16        // dst-range buckets for CSR build
#define NBKT (NNODES / NB)
#define BCAP 81920   // per-bucket stage capacity
#define KB 64        // blocks per bucket in count_rank/fill2
#define BZT 1024     // bucketize block size
#define NSL 4        // feature slices (32 features = 64 B rows)

typedef __attribute__((ext_vector_type(8))) short short8;
typedef __attribute__((ext_vector_type(4))) float floatx4;
typedef __attribute__((ext_vector_type(4))) unsigned int uintx4;
typedef unsigned int uint32;
typedef unsigned long long ull;
typedef unsigned short ushort16;

__device__ __forceinline__ float blo(uint32 u) { return __uint_as_float(u << 16); }
__device__ __forceinline__ float bhi(uint32 u) { return __uint_as_float(u & 0xffff0000u); }
__device__ __forceinline__ ushort16 f2b(float f) {
    __hip_bfloat16 h = __float2bfloat16(f);
    return *reinterpret_cast<ushort16*>(&h);
}
__device__ __forceinline__ uint32 pack2(float a, float b) {
    return (uint32)f2b(a) | ((uint32)f2b(b) << 16);
}

// ---------------- CSR build ----------------
// Pass A: bucket compaction only. Stage word: lo=src, hi=dst.

__global__ __launch_bounds__(BZT) void bucketize(const int* __restrict__ src,
                                                 const int* __restrict__ dst,
                                                 int* __restrict__ bcursor,
                                                 ull* __restrict__ stage, int E) {
    __shared__ int cnt[NB], lbase[NB], gbase[NB];
    __shared__ int2 buf[BZT];
    __shared__ unsigned char bb[BZT];
    int t = threadIdx.x;
    int e0 = blockIdx.x * BZT;
    int e = e0 + t;
    if (t < NB) cnt[t] = 0;
    __syncthreads();
    int s = 0, d = 0, b = 0, r = 0;
    bool valid = e < E;
    if (valid) {
        s = src[e];
        d = dst[e];
        b = d / NBKT;
        r = atomicAdd(&cnt[b], 1);
    }
    __syncthreads();
    if (t == 0) {
        int run = 0;
        for (int i = 0; i < NB; i++) { lbase[i] = run; run += cnt[i]; }
    }
    __syncthreads();
    if (valid) {
        int p = lbase[b] + r;
        buf[p] = make_int2(s, d);
        bb[p] = (unsigned char)b;
    }
    if (t < NB) gbase[t] = atomicAdd(&bcursor[t], cnt[t]);
    __syncthreads();
    int nvalid = min(BZT, E - e0);
    if (t < nvalid) {
        int b2 = bb[t];
        int2 sd = buf[t];
        int pos = gbase[b2] + (t - lbase[b2]);
        if (pos < BCAP) {
            ull val = (ull)(unsigned)sd.x | ((ull)(unsigned)sd.y << 32);
            __builtin_nontemporal_store(val, &stage[(size_t)b2 * BCAP + pos]);
        }
    }
}

// Pass B: per-node degree count + rank, XCD-local atomics (bucket b -> XCD b%8).

__global__ __launch_bounds__(256) void count_rank(const ull* __restrict__ stage,
                                                  const int* __restrict__ bcursor,
                                                  int* __restrict__ counts,
                                                  int* __restrict__ rnk) {
    int blk = blockIdx.x;
    int b = (blk & 7) + 8 * ((blk >> 3) & 1);  // home XCD = b%8
    int slot = blk >> 4;
    int cntb = min(bcursor[b], BCAP);
    int per = (cntb + KB - 1) / KB;
    int s0 = slot * per;
    int s1 = min(s0 + per, cntb);
    const ull* st = stage + (size_t)b * BCAP;
    int* rk = rnk + (size_t)b * BCAP;
    for (int i = s0 + threadIdx.x; i < s1; i += 256) {
        ull v = st[i];
        int d = (int)(unsigned)(v >> 32);
        rk[i] = atomicAdd(&counts[d], 1);
    }
}

// Pass C: atomic-free scatter within bucket's csr window (natural node order).

__global__ __launch_bounds__(256) void fill2(const ull* __restrict__ stage,
                                             const int* __restrict__ rnk,
                                             const int* __restrict__ bcursor,
                                             const int* __restrict__ offs,
                                             int* __restrict__ csr) {
    int blk = blockIdx.x;
    int b = (blk & 7) + 8 * ((blk >> 3) & 1);
    int slot = blk >> 4;
    int cntb = min(bcursor[b], BCAP);
    int per = (cntb + KB - 1) / KB;
    int s0 = slot * per;
    int s1 = min(s0 + per, cntb);
    const ull* st = stage + (size_t)b * BCAP;
    const int* rk = rnk + (size_t)b * BCAP;
    for (int i = s0 + threadIdx.x; i < s1; i += 256) {
        ull v = st[i];
        int s = (int)(v & 0xffffffffu);
        int d = (int)(unsigned)(v >> 32);
        csr[offs[d] + rk[i]] = s;
    }
}

// scan of counts padded to 8 -> offs (32 B-aligned csr runs)
__global__ void scan1(const int* __restrict__ counts, int* __restrict__ offs,
                      int* __restrict__ bsum, int N) {
    __shared__ int tmp[256];
    int t = threadIdx.x;
    int i = blockIdx.x * 256 + t;
    int v = (i < N) ? ((counts[i] + 7) & ~7) : 0;
    tmp[t] = v;
    __syncthreads();
    for (int d = 1; d < 256; d <<= 1) {
        int add = (t >= d) ? tmp[t - d] : 0;
        __syncthreads();
        tmp[t] += add;
        __syncthreads();
    }
    if (i < N) offs[i] = tmp[t] - v;
    if (t == 255) bsum[blockIdx.x] = tmp[255];
}

__global__ void scan2(int* __restrict__ bsum, int nb) {
    __shared__ int tmp[512];
    int t = threadIdx.x;
    int v = (t < nb) ? bsum[t] : 0;
    tmp[t] = v;
    __syncthreads();
    for (int d = 1; d < 512; d <<= 1) {
        int add = (t >= d) ? tmp[t - d] : 0;
        __syncthreads();
        tmp[t] += add;
        __syncthreads();
    }
    if (t < nb) bsum[t] = tmp[t] - v;
}

// finalize offs, inv, and write csr pad entries (-> zero row)
__global__ void scan3(int* __restrict__ offs, const int* __restrict__ bsum,
                      const int* __restrict__ counts, float* __restrict__ invs,
                      int* __restrict__ csr, int N) {
    int i = blockIdx.x * 256 + threadIdx.x;
    if (i < N) {
        int o = offs[i] + bsum[blockIdx.x];
        offs[i] = o;
        int c = counts[i];
        invs[i] = 1.0f / (float)(c + 1);
        int c8 = (c + 7) & ~7;
        for (int k = c; k < c8; k++) csr[o + k] = NNODES;
    }
}

// ---------------- pack all weights + zero pad rows (one dispatch) ----------------

__global__ void pack_all(const float* __restrict__ W1, const float* __restrict__ W2,
                         const float* __restrict__ W3, const float* __restrict__ W4,
                         ushort16* __restrict__ Wp1, ushort16* __restrict__ Wp2,
                         ushort16* __restrict__ Wp3, ushort16* __restrict__ Wp4,
                         uint32* __restrict__ zb, uint32* __restrict__ hb,
                         uint32* __restrict__ z16b) {
    int blk = blockIdx.x;
    int lane = threadIdx.x;  // 64
    if (blk < 128) {
        int w = blk >> 5, b = blk & 31;
        const float* W = w == 0 ? W1 : w == 1 ? W2 : w == 2 ? W3 : W4;
        ushort16* Wp = w == 0 ? Wp1 : w == 1 ? Wp2 : w == 2 ? Wp3 : Wp4;
        int nt = b >> 2, ks = b & 3;
        int n = nt * 16 + (lane & 15);
        int kbase = ks * 32 + ((lane >> 4) << 3);
        ushort16 tmp[8];
#pragma unroll
        for (int i = 0; i < 8; i++) tmp[i] = f2b(W[(size_t)(kbase + i) * HID + n]);
        *(uint4*)&Wp[((size_t)b * 64 + lane) * 8] = *(uint4*)tmp;
    } else {
        for (int i = lane; i < 4 * 8 * 16; i += 64) {
            int s = i >> 7, rem = i & 127, r = rem >> 4, k = rem & 15;
            zb[((size_t)s * NP + NNODES + r) * 16 + k] = 0;
            hb[((size_t)s * NP + NNODES + r) * 16 + k] = 0;
        }
        for (int i = lane; i < 64; i += 64)
            z16b[(size_t)(NNODES + (i >> 3)) * 8 + (i & 7)] = 0;
    }
}

// ---------------- MFMA GEMM: Z(sliced [4][NP][32] bf16) = A @ W ----------------
// 256 rows per block (4 row-tiles), W staged to LDS once per block.

template <int AF32>
__global__ __launch_bounds__(256) void gemm_mfma(const void* __restrict__ Av,
                                                 const ushort16* __restrict__ Wp,
                                                 ushort16* __restrict__ Z, int M) {
    __shared__ __align__(16) ushort16 Wl[32 * 64 * 8];  // 32 KB
    int t = threadIdx.x;
    const uint4* wp4 = (const uint4*)Wp;
    uint4* wl4 = (uint4*)Wl;
#pragma unroll
    for (int p = 0; p < 8; p++) wl4[t + p * 256] = wp4[t + p * 256];
    __syncthreads();

    int wv = t >> 6, lane = t & 63;
    int kb = (lane >> 4) << 3;  // 0,8,16,24
    int c4 = (lane >> 4) << 2;  // 0,4,8,12

    for (int rt = 0; rt < 4; rt++) {
        int row = blockIdx.x * 256 + rt * 64 + wv * 16 + (lane & 15);
        int rowc = min(row, M - 1);

        short8 a[4];
        if (AF32) {
            const float* A = (const float*)Av;
#pragma unroll
            for (int ks = 0; ks < 4; ks++) {
                const float* p = A + (size_t)rowc * HID + ks * 32 + kb;
                floatx4 lo = *(const floatx4*)p;
                floatx4 hi = *(const floatx4*)(p + 4);
                union { short8 s; ushort16 u[8]; } cv;
                cv.u[0] = f2b(lo.x); cv.u[1] = f2b(lo.y); cv.u[2] = f2b(lo.z); cv.u[3] = f2b(lo.w);
                cv.u[4] = f2b(hi.x); cv.u[5] = f2b(hi.y); cv.u[6] = f2b(hi.z); cv.u[7] = f2b(hi.w);
                a[ks] = cv.s;
            }
        } else {
            const ushort16* A = (const ushort16*)Av;
#pragma unroll
            for (int ks = 0; ks < 4; ks++)
                a[ks] = *(const short8*)(A + ((size_t)ks * NP + rowc) * 32 + kb);
        }

        floatx4 acc[8];
#pragma unroll
        for (int nt = 0; nt < 8; nt++) acc[nt] = (floatx4){0.f, 0.f, 0.f, 0.f};

#pragma unroll
        for (int nt = 0; nt < 8; nt++) {
#pragma unroll
            for (int ks = 0; ks < 4; ks++) {
                short8 w = *(const short8*)&Wl[(size_t)(((nt << 2) | ks) * 64 + lane) * 8];
                acc[nt] = __builtin_amdgcn_mfma_f32_16x16x32_bf16(w, a[ks], acc[nt], 0, 0, 0);
            }
        }

        if (row < M) {
#pragma unroll
            for (int nt = 0; nt < 8; nt++) {
                int col = nt * 16 + c4;
                int sl = col >> 5, off2 = col & 31;
                union { ushort16 u[4]; uint2 v; } pk;
                pk.u[0] = f2b(acc[nt][0]);
                pk.u[1] = f2b(acc[nt][1]);
                pk.u[2] = f2b(acc[nt][2]);
                pk.u[3] = f2b(acc[nt][3]);
                *(uint2*)&Z[((size_t)sl * NP + row) * 32 + off2] = pk.v;
            }
        }
    }
}

// ---------------- sliced aggregate: 4 slices x 64 B rows, 4 lanes/node ----------------

#define ACCN(acc0, acc1, acc2, acc3, g)                \
    {                                                  \
        acc0.x += blo((g).x); acc0.y += bhi((g).x);    \
        acc1.x += blo((g).y); acc1.y += bhi((g).y);    \
        acc2.x += blo((g).z); acc2.y += bhi((g).z);    \
        acc3.x += blo((g).w); acc3.y += bhi((g).w);    \
    }

__global__ __launch_bounds__(256) void agg_sliced(const uint32* __restrict__ Z,
                                                  const int* __restrict__ offs,
                                                  const int* __restrict__ counts,
                                                  const int* __restrict__ csr,
                                                  const float* __restrict__ invs,
                                                  const float* __restrict__ bias,
                                                  uint32* __restrict__ H, int N) {
    int s = blockIdx.x & 3;
    int chunk = blockIdx.x >> 2;
    int t = threadIdx.x;
    int l = t & 3;                // 16 B quarter of the 64 B row
    int p = chunk * 64 + (t >> 2);
    bool act = p < N;
    int pc = act ? p : N - 1;
    const uint4* Zs = (const uint4*)(Z + (size_t)s * NP * 16);
    uint4* Hs = (uint4*)(H + (size_t)s * NP * 16);

    int beg = offs[pc];
    int cnt8 = (counts[pc] + 7) & ~7;
    float sc = invs[pc];

    uint4 sv = Zs[(size_t)pc * 4 + l];
    float2 acc0 = make_float2(blo(sv.x), bhi(sv.x));
    float2 acc1 = make_float2(blo(sv.y), bhi(sv.y));
    float2 acc2 = make_float2(blo(sv.z), bhi(sv.z));
    float2 acc3 = make_float2(blo(sv.w), bhi(sv.w));

    for (int j = 0; j < cnt8; j += 8) {
        int4 ia = *(const int4*)&csr[beg + j];
        int4 ib = *(const int4*)&csr[beg + j + 4];
        uint4 g[8];
        g[0] = Zs[(size_t)ia.x * 4 + l];
        g[1] = Zs[(size_t)ia.y * 4 + l];
        g[2] = Zs[(size_t)ia.z * 4 + l];
        g[3] = Zs[(size_t)ia.w * 4 + l];
        g[4] = Zs[(size_t)ib.x * 4 + l];
        g[5] = Zs[(size_t)ib.y * 4 + l];
        g[6] = Zs[(size_t)ib.z * 4 + l];
        g[7] = Zs[(size_t)ib.w * 4 + l];
#pragma unroll
        for (int q = 0; q < 8; q++) ACCN(acc0, acc1, acc2, acc3, g[q]);
    }

    const float* bp = bias + s * 32 + l * 8;
    floatx4 b01 = *(const floatx4*)bp;
    floatx4 b23 = *(const floatx4*)(bp + 4);
    uintx4 o;
    o.x = pack2(fmaxf(acc0.x * sc + b01.x, 0.f), fmaxf(acc0.y * sc + b01.y, 0.f));
    o.y = pack2(fmaxf(acc1.x * sc + b01.z, 0.f), fmaxf(acc1.y * sc + b01.w, 0.f));
    o.z = pack2(fmaxf(acc2.x * sc + b23.x, 0.f), fmaxf(acc2.y * sc + b23.y, 0.f));
    o.w = pack2(fmaxf(acc3.x * sc + b23.z, 0.f), fmaxf(acc3.y * sc + b23.w, 0.f));
    if (act) __builtin_nontemporal_store(o, (uintx4*)&Hs[(size_t)p * 4 + l]);
}

// ---------------- layer 5: Z16[NP][16] bf16 = H(sliced [4][NP][16u32]) @ W5 ----------------

__global__ __launch_bounds__(256) void gemm16(const uint32* __restrict__ A,
                                              const float* __restrict__ W5,
                                              uint32* __restrict__ Z16, int M) {
    __shared__ float Ws[HID * OUTF];  // 8 KB
    int t = threadIdx.x;
    for (int i = t; i < HID * OUTF; i += 256) Ws[i] = W5[i];
    __syncthreads();
    int gid = blockIdx.x * 256 + t;
    int r = gid >> 3, cp = gid & 7;
    if (r >= M) return;
    float a0 = 0.f, a1 = 0.f;
#pragma unroll
    for (int s4 = 0; s4 < 4; s4++) {
        const uint32* ar = A + ((size_t)s4 * NP + r) * 16;
#pragma unroll
        for (int k = 0; k < 16; k++) {
            uint32 u = ar[k];
            float f0 = blo(u), f1 = bhi(u);
            a0 += f0 * Ws[(s4 * 32 + 2 * k) * OUTF + 2 * cp] +
                  f1 * Ws[(s4 * 32 + 2 * k + 1) * OUTF + 2 * cp];
            a1 += f0 * Ws[(s4 * 32 + 2 * k) * OUTF + 2 * cp + 1] +
                  f1 * Ws[(s4 * 32 + 2 * k + 1) * OUTF + 2 * cp + 1];
        }
    }
    Z16[(size_t)r * 8 + cp] = pack2(a0, a1);
}

// ---------------- layer 5 aggregate + bias + log_softmax ----------------

__global__ __launch_bounds__(256) void agg16_lsm(const uint32* __restrict__ Z16,
                                                 const int* __restrict__ offs,
                                                 const int* __restrict__ counts,
                                                 const int* __restrict__ csr,
                                                 const float* __restrict__ invs,
                                                 const float* __restrict__ b5,
                                                 float* __restrict__ out, int N) {
    int t = threadIdx.x;
    int l = t & 1;
    int p = blockIdx.x * 128 + (t >> 1);
    bool act = p < N;
    int pc = act ? p : N - 1;
    const uint4* Zs = (const uint4*)Z16;

    uint4 sv = Zs[(size_t)pc * 2 + l];
    float2 acc0 = make_float2(blo(sv.x), bhi(sv.x));
    float2 acc1 = make_float2(blo(sv.y), bhi(sv.y));
    float2 acc2 = make_float2(blo(sv.z), bhi(sv.z));
    float2 acc3 = make_float2(blo(sv.w), bhi(sv.w));

    int beg = offs[pc];
    int cnt8 = (counts[pc] + 7) & ~7;
    for (int j = 0; j < cnt8; j += 8) {
        int4 ia = *(const int4*)&csr[beg + j];
        int4 ib = *(const int4*)&csr[beg + j + 4];
        uint4 g[8];
        g[0] = Zs[(size_t)ia.x * 2 + l];
        g[1] = Zs[(size_t)ia.y * 2 + l];
        g[2] = Zs[(size_t)ia.z * 2 + l];
        g[3] = Zs[(size_t)ia.w * 2 + l];
        g[4] = Zs[(size_t)ib.x * 2 + l];
        g[5] = Zs[(size_t)ib.y * 2 + l];
        g[6] = Zs[(size_t)ib.z * 2 + l];
        g[7] = Zs[(size_t)ib.w * 2 + l];
#pragma unroll
        for (int q = 0; q < 8; q++) ACCN(acc0, acc1, acc2, acc3, g[q]);
    }

    float sc = invs[pc];
    const float* bp = b5 + l * 8;
    floatx4 b01 = *(const floatx4*)bp;
    floatx4 b23 = *(const floatx4*)(bp + 4);
    float val[8];
    val[0] = acc0.x * sc + b01.x; val[1] = acc0.y * sc + b01.y;
    val[2] = acc1.x * sc + b01.z; val[3] = acc1.y * sc + b01.w;
    val[4] = acc2.x * sc + b23.x; val[5] = acc2.y * sc + b23.y;
    val[6] = acc3.x * sc + b23.z; val[7] = acc3.y * sc + b23.w;
    float mm = val[0];
#pragma unroll
    for (int k = 1; k < 8; k++) mm = fmaxf(mm, val[k]);
    mm = fmaxf(mm, __shfl_xor(mm, 1, 64));
    float ss = 0.f;
#pragma unroll
    for (int k = 0; k < 8; k++) ss += expf(val[k] - mm);
    ss += __shfl_xor(ss, 1, 64);
    float ls = mm + logf(ss);
    if (act) {
        float4 o0 = make_float4(val[0] - ls, val[1] - ls, val[2] - ls, val[3] - ls);
        float4 o1 = make_float4(val[4] - ls, val[5] - ls, val[6] - ls, val[7] - ls);
        float* op = out + (size_t)p * OUTF + l * 8;
        *(float4*)op = o0;
        *(float4*)(op + 4) = o1;
    }
}

// ---------------- launch ----------------

extern "C" void kernel_launch(void* const* d_in, const int* in_sizes, int n_in,
                              void* d_out, int out_size, void* d_ws, size_t ws_size,
                              hipStream_t stream) {
    const float* x   = (const float*)d_in[0];
    const int*   src = (const int*)d_in[1];
    const int*   dst = (const int*)d_in[2];
    const float* W1 = (const float*)d_in[3];
    const float* b1 = (const float*)d_in[4];
    const float* W2 = (const float*)d_in[5];
    const float* b2 = (const float*)d_in[6];
    const float* W3 = (const float*)d_in[7];
    const float* b3 = (const float*)d_in[8];
    const float* W4 = (const float*)d_in[9];
    const float* b4 = (const float*)d_in[10];
    const float* W5 = (const float*)d_in[11];
    const float* b5 = (const float*)d_in[12];

    char* ws = (char*)d_ws;
    size_t off = 0;
    auto alloc = [&](size_t bytes) {
        void* p = ws + off;
        off = (off + bytes + 255) & ~(size_t)255;
        return p;
    };
    const size_t CSR_ELEMS = (size_t)NEDGES + 7 * (size_t)NNODES + 64;
    ushort16* zb   = (ushort16*)alloc((size_t)NSL * NP * 32 * 2);
    ushort16* hb   = (ushort16*)alloc((size_t)NSL * NP * 32 * 2);
    uint32*   z16b = (uint32*)alloc((size_t)NP * OUTF * 2);
    int*      counts = (int*)alloc((size_t)(NNODES + NB) * 4);  // counts + bcursor (one memset)
    int*      bcursor = counts + NNODES;
    float*    invs   = (float*)alloc((size_t)NNODES * 4);
    int*      offs   = (int*)alloc((size_t)(NNODES + 1) * 4);
    int*      bsum   = (int*)alloc(512 * 4);
    int*      csr    = (int*)alloc(CSR_ELEMS * 4);
    ull*      stage  = (ull*)alloc((size_t)NB * BCAP * 8);
    int*      rnk    = (int*)alloc((size_t)NB * BCAP * 4);
    ushort16* Wp1 = (ushort16*)alloc((size_t)HID * HID * 2);
    ushort16* Wp2 = (ushort16*)alloc((size_t)HID * HID * 2);
    ushort16* Wp3 = (ushort16*)alloc((size_t)HID * HID * 2);
    ushort16* Wp4 = (ushort16*)alloc((size_t)HID * HID * 2);
    (void)ws_size; (void)in_sizes; (void)n_in; (void)out_size;

    const int N = NNODES, E = NEDGES;
    int nb = (N + 255) / 256;

    // CSR build (natural node order; no degree sort)
    hipMemsetAsync(counts, 0, (size_t)(NNODES + NB) * 4, stream);
    bucketize<<<(E + BZT - 1) / BZT, BZT, 0, stream>>>(src, dst, bcursor, stage, E);
    count_rank<<<NB * KB, 256, 0, stream>>>(stage, bcursor, counts, rnk);
    scan1<<<nb, 256, 0, stream>>>(counts, offs, bsum, N);
    scan2<<<1, 512, 0, stream>>>(bsum, nb);
    scan3<<<nb, 256, 0, stream>>>(offs, bsum, counts, invs, csr, N);
    fill2<<<NB * KB, 256, 0, stream>>>(stage, rnk, bcursor, offs, csr);
    pack_all<<<129, 64, 0, stream>>>(W1, W2, W3, W4, Wp1, Wp2, Wp3, Wp4,
                                     (uint32*)zb, (uint32*)hb, z16b);

    int gemmGrid = (N + 255) / 256;
    int aggGrid  = NSL * ((N + 63) / 64);
    int agg16Grid = (N + 127) / 128;

    gemm_mfma<1><<<gemmGrid, 256, 0, stream>>>((const void*)x, Wp1, zb, N);
    agg_sliced<<<aggGrid, 256, 0, stream>>>((const uint32*)zb, offs, counts, csr, invs, b1,
                                            (uint32*)hb, N);

    gemm_mfma<0><<<gemmGrid, 256, 0, stream>>>((const void*)hb, Wp2, zb, N);
    agg_sliced<<<aggGrid, 256, 0, stream>>>((const uint32*)zb, offs, counts, csr, invs, b2,
                                            (uint32*)hb, N);

    gemm_mfma<0><<<gemmGrid, 256, 0, stream>>>((const void*)hb, Wp3, zb, N);
    agg_sliced<<<aggGrid, 256, 0, stream>>>((const uint32*)zb, offs, counts, csr, invs, b3,
                                            (uint32*)hb, N);

    gemm_mfma<0><<<gemmGrid, 256, 0, stream>>>((const void*)hb, Wp4, zb, N);
    agg_sliced<<<aggGrid, 256, 0, stream>>>((const uint32*)zb, offs, counts, csr, invs, b4,
                                            (uint32*)hb, N);

    gemm16<<<(N * 8 + 255) / 256, 256, 0, stream>>>((const uint32*)hb, W5, z16b, N);
    agg16_lsm<<<agg16Grid, 256, 0, stream>>>(z16b, offs, counts, csr, invs, b5,
                                             (float*)d_out, N);
}